// Round 5
// baseline (144.581 us; speedup 1.0000x reference)
//
#include <hip/hip_runtime.h>

// QuadraticConv2D: B=8 H=56 W=56 C=64 O=128, 55 quadratic pairs over (ones + 9 shifts)
// GEMM M=25088 pixels, K=55x64, N=128.
// R17 = R15 (col-half split: 512thr, 8 waves = 2/SIMD, wave=(nq,ch), 2 m-tiles/wave,
// full K, spill-free ~150 regs) + B-prefetch ring deepened 11 -> 22.
// R16 (R12 + depth 22) crashed: 248+ register need at the 256-arch boundary ->
// spill under outstanding asm loads -> clobbered address reg -> memory fault.
// R15's slimmer footprint (sv 48 + acc 32 + ring 88 + temps ~= 200) fits the
// 256/wave budget at 2 waves/SIMD with margin. Concurrency model (fits R12/R15):
// time ~= B_bytes_per_CU / inflight_bytes x latency. R15: 1.8MB/88KB*5kcyc=47us.
// R17: 1.8MB/176KB*5kcyc ~= 23us. Slot scheme: flat step s = 55*ks+p, slot =
// ring[(s/11)&1][s%11]; (s/11)&1 = (ki + p/11)&1 with ks=ko*2+ki, ki unrolled ->
// all ring indices compile-time. Refill s+22 lands in the SAME slot. 224 blocks.

#define CB 8
#define CH 56
#define CW 56
#define CC 64
#define CO 128
#define RS 72   // row stride in f16 (144 B)

typedef __attribute__((ext_vector_type(8))) _Float16 v8hf;  // MFMA A/B frag (4 VGPRs)
typedef __attribute__((ext_vector_type(16))) float f16f;    // 32x32 accumulator
typedef __attribute__((address_space(3))) const _Float16 lds_cf16;

// pair tables: p-th pair (i,j), i=0..9, j=i..9 (reference order)
__device__ constexpr int PII[55] = {0,0,0,0,0,0,0,0,0,0, 1,1,1,1,1,1,1,1,1, 2,2,2,2,2,2,2,2,
                                    3,3,3,3,3,3,3, 4,4,4,4,4,4, 5,5,5,5,5, 6,6,6,6, 7,7,7, 8,8, 9};
__device__ constexpr int PJJ[55] = {0,1,2,3,4,5,6,7,8,9, 1,2,3,4,5,6,7,8,9, 2,3,4,5,6,7,8,9,
                                    3,4,5,6,7,8,9, 4,5,6,7,8,9, 5,6,7,8,9, 6,7,8,9, 7,8,9, 8,9, 9};

// ---- prep: kernel [55][64][128] f32 -> BtF [55][4 ks][4 nq][64 lane][8] f16
// (exact per-wave MFMA B-fragment order: n = nq*32+(lane&31), k = ks*16+(lane>>5)*8+e)
__global__ __launch_bounds__(256) void prep_kernel(const float* __restrict__ K,
                                                   _Float16* __restrict__ BtF) {
  __shared__ float tile[CC * CO];
  const int p = blockIdx.x;
  const int t = threadIdx.x;
  const float* src = K + (size_t)p * CC * CO;
#pragma unroll
  for (int e = 0; e < 8; ++e) {
    const int idx = t * 4 + e * 1024;
    *(float4*)&tile[idx] = *(const float4*)&src[idx];
  }
  __syncthreads();
#pragma unroll
  for (int e4 = 0; e4 < 4; ++e4) {
    const int idx = e4 * 256 + t;          // 0..1023 = ((ks*4 + nq)*64 + lane)
    const int lane = idx & 63;
    const int nqq = (idx >> 6) & 3;
    const int ksq = idx >> 8;
    const int n = nqq * 32 + (lane & 31);
    const int kb = ksq * 16 + (lane >> 5) * 8;
    _Float16 ov[8];
#pragma unroll
    for (int e = 0; e < 8; ++e)
      ov[e] = (_Float16)tile[(kb + e) * CO + n];
    *(v8hf*)(BtF + ((size_t)p * 1024 + idx) * 8) = *(const v8hf*)ov;
  }
}

// ---- main: one block per (b, row-pair). 512 threads = 8 waves (2/SIMD).
// Wave (nq, ch): N-quarter nq, col-half ch. Wave computes 2 complete m-tiles:
// rows h0,h0+1 x cols ch*32..ch*32+31 (ch=1 cols >=56 are pad). Full K loop.
__global__ __launch_bounds__(512, 1) void quad_kernel(const float* __restrict__ in,
                                                      const _Float16* __restrict__ BtF,
                                                      float* __restrict__ out) {
  __shared__ _Float16 rowsH[4][64][RS];   // rows h0-1..h0+2 (f16), col = w+1 halo, 36.9 KB

  const int t = threadIdx.x;
  const int b = blockIdx.x / (CH / 2);
  const int h0 = (blockIdx.x % (CH / 2)) * 2;

  // stage 4 input rows into LDS (f16) with zero halo (w=-1, w>=56) / zero OOB rows
  // 512 threads: 8 threads/col, 8 channels each
  {
    const int col = t >> 3;          // 0..63
    const int cg = (t & 7) * 8;      // 8-channel group
    const int w = col - 1;
#pragma unroll
    for (int r = 0; r < 4; ++r) {
      const int hh = h0 + r - 1;
      const bool valid = (hh >= 0) && (hh < CH) && (w >= 0) && (w < CW);
      float4 v0 = make_float4(0.f, 0.f, 0.f, 0.f), v1 = v0;
      if (valid) {
        const float* s = in + (((size_t)(b * CH + hh)) * CW + w) * CC + cg;
        v0 = *(const float4*)(s);
        v1 = *(const float4*)(s + 4);
      }
      _Float16 pv[8];
      pv[0] = (_Float16)v0.x; pv[1] = (_Float16)v0.y; pv[2] = (_Float16)v0.z; pv[3] = (_Float16)v0.w;
      pv[4] = (_Float16)v1.x; pv[5] = (_Float16)v1.y; pv[6] = (_Float16)v1.z; pv[7] = (_Float16)v1.w;
      *(v8hf*)&rowsH[r][col][cg] = *(const v8hf*)&pv[0];
    }
  }

  const int lane = t & 63;
  const int wv = t >> 6;        // wave 0..7
  const int nq = wv & 3;        // N-quarter 0..3
  const int ch = wv >> 2;       // col-half 0..1 (waves wv, wv+4 share a SIMD & B stream)
  const int ml = lane & 31;     // 32x32 MFMA: m (A) / n (B) lane index
  const int hk = lane >> 5;     // k-half selector within MFMA frag
  const int h8 = hk * 8;
  const int cb = ch * 32;       // col base for this wave's m-tiles

  f16f acc0, acc1;              // rows h0, h0+1
#pragma unroll
  for (int r = 0; r < 16; ++r) { acc0[r] = 0.f; acc1[r] = 0.f; }

  // wave's B base: BtF + ((p*4 + ks)*4 + nq)*512 + lane*8 (coalesced 1 KB per load)
  const _Float16* Bw = BtF + (size_t)(nq * 64 + lane) * 8;
  const v8hf vone = {1, 1, 1, 1, 1, 1, 1, 1};

  // AS3 base pointer for asm ds_read (addrspacecast, 32-bit operand)
  lds_cf16* lds3 = (lds_cf16*)&rowsH[0][0][0];

  // prefetch ring, depth 22 = 2 x 11 (asm loads; issue order pinned by volatile)
  // flat step s = ks*55 + p; physical slot = ring[(s/11)&1][s%11]; element offset
  // = p*8192 + ks*2048. (s/11)&1 = (ki + p/11)&1 with ks = ko*2+ki.
  v8hf ring[2][11];
#pragma unroll
  for (int p = 0; p < 22; ++p) {
    const _Float16* ba = Bw + (size_t)p * 8192;   // steps 0..21, all ks=0
    asm volatile("global_load_dwordx4 %0, %1, off" : "=v"(ring[(p / 11) & 1][p % 11]) : "v"(ba));
  }

  __syncthreads();  // rowsH ready; no further barriers

#pragma unroll 1
  for (int ko = 0; ko < 2; ++ko) {
#pragma unroll
    for (int ki = 0; ki < 2; ++ki) {     // ki compile-time -> ring indices fold
      const int ks = ko * 2 + ki;        // K=64 channels in 4 steps of 16
      const int koff = ks * 16 + h8;
      // 12 shift vectors for this wave's col-half: sv[rr*3+dx] = rowsH[rr][cb+ml+dx][koff]
      v8hf sv[12];
#pragma unroll
      for (int rr = 0; rr < 4; ++rr)
#pragma unroll
        for (int dx = 0; dx < 3; ++dx) {
          int c = cb + ml + dx;           // ch=0: max 33; ch=1: max 65 -> clamp
          c = c > 63 ? 63 : c;            // cols >=57 staged zero, clamp is safe
          lds_cf16* p0 = lds3 + (rr * 64 + c) * RS + koff;
          asm volatile("ds_read_b128 %0, %1" : "=v"(sv[rr * 3 + dx]) : "v"(p0));
        }
      // one wait for all 12; ties the values so uses can't float above it
      asm volatile("s_waitcnt lgkmcnt(0)"
                   : "+v"(sv[0]), "+v"(sv[1]), "+v"(sv[2]), "+v"(sv[3]),
                     "+v"(sv[4]), "+v"(sv[5]), "+v"(sv[6]), "+v"(sv[7]),
                     "+v"(sv[8]), "+v"(sv[9]), "+v"(sv[10]), "+v"(sv[11]));

      const int ksn = (ks < 3) ? ks + 1 : 3;  // tail prefetch clamp (redundant, harmless)
#pragma unroll
      for (int p = 0; p < 55; ++p) {
        const int ri = (ki + p / 11) & 1;   // ring parity, compile-time
        // wait until the slot's load (issued 22 steps ago) has landed; 21 newer in flight
        asm volatile("s_waitcnt vmcnt(21)" : "+v"(ring[ri][p % 11]));
        const v8hf bb = ring[ri][p % 11];
        // refill the slot with flat step s+22 (same physical slot; address folds)
        {
          const int p2 = (p < 33) ? p + 22 : p - 33;
          const int ks2 = (p < 33) ? ks : ksn;
          const _Float16* ba = Bw + (size_t)p2 * 8192 + (size_t)ks2 * 2048;
          asm volatile("global_load_dwordx4 %0, %1, off" : "=v"(ring[ri][p % 11]) : "v"(ba));
        }
        const int pi = PII[p], pj = PJJ[p];
        v8hf a0, a1;
        if (pi == 0) {
          if (pj == 0) { a0 = vone; a1 = vone; }
          else {
            const int dy = (pj - 1) / 3, dx = (pj - 1) % 3;
            a0 = sv[dy * 3 + dx];
            a1 = sv[(dy + 1) * 3 + dx];
          }
        } else {
          const int dyi = (pi - 1) / 3, dxi = (pi - 1) % 3;
          const int dyj = (pj - 1) / 3, dxj = (pj - 1) % 3;
          a0 = sv[dyi * 3 + dxi] * sv[dyj * 3 + dxj];
          a1 = sv[(dyi + 1) * 3 + dxi] * sv[(dyj + 1) * 3 + dxj];
        }
        acc0 = __builtin_amdgcn_mfma_f32_32x32x16_f16(a0, bb, acc0, 0, 0, 0);
        acc1 = __builtin_amdgcn_mfma_f32_32x32x16_f16(a1, bb, acc1, 0, 0, 0);
      }
    }
  }
  // drain the 22 stray tail prefetches before the epilogue
  asm volatile("s_waitcnt vmcnt(0)");

  // epilogue: 32x32 C/D layout col=lane&31 (n), row=(reg&3)+8*(reg>>2)+4*(lane>>5) (m)
#pragma unroll
  for (int rw = 0; rw < 2; ++rw) {
    float* ob = out + ((size_t)(b * CH + h0 + rw) * CW + cb) * CO + nq * 32 + ml;
    const f16f accc = rw ? acc1 : acc0;
    if (ch == 0) {
#pragma unroll
      for (int r = 0; r < 16; ++r) {  // w = 0..31, all real
        const int wp = (r & 3) + 8 * (r >> 2) + 4 * hk;
        ob[(size_t)wp * CO] = accc[r];
      }
    } else {
#pragma unroll
      for (int r = 0; r < 12; ++r) {  // w = 32..55; regs 12..15 are w>=56 pad
        const int wp = (r & 3) + 8 * (r >> 2) + 4 * hk;
        ob[(size_t)wp * CO] = accc[r];
      }
    }
  }
}

extern "C" void kernel_launch(void* const* d_in, const int* in_sizes, int n_in,
                              void* d_out, int out_size, void* d_ws, size_t ws_size,
                              hipStream_t stream) {
  const float* in = (const float*)d_in[0];      // [8,56,56,64] f32
  const float* K = (const float*)d_in[1];       // [55,64,128] f32
  float* out = (float*)d_out;                   // [8,56,56,128] f32
  _Float16* BtF = (_Float16*)d_ws;              // [55][4][4][64][8] f16 = 901,120 B
  (void)in_sizes; (void)n_in; (void)out_size; (void)ws_size;

  prep_kernel<<<55, 256, 0, stream>>>(K, BtF);
  quad_kernel<<<CB * (CH / 2), 512, 0, stream>>>(in, BtF, out);
}

// Round 6
// 90.652 us; speedup vs baseline: 1.5949x; 1.5949x over previous
//
#include <hip/hip_runtime.h>

// QuadraticConv2D: B=8 H=56 W=56 C=64 O=128, 55 quadratic pairs over (ones + 9 shifts)
// GEMM M=25088 pixels, K=55x64, N=128.
// R18 = R12 exactly (known-best 40us quad: 256thr, wave=nq, 4 m-tiles/wave, ring 11,
// spill-free) + ONE change: BtF replicated 4x to break the L2 convoy. Theory: all
// 224 blocks walk the same B address sequence in lockstep; within an XCD, 28 CUs
// hit the same line -> one L2 bank serializes 28 requesters -> effective latency
// ~4800 cyc (= measured 44KB/22.5GB/s/CU) vs ~200 cyc L2 hit. 4 copies selected by
// (blockIdx>>3)&3 split each XCD's CUs into ~7-CU streams. Copy stride padded
// +256 B: 901120/64 = 14080 = 0 mod 16, so unpadded copies would map the same
// logical line to the SAME bank; +4 lines rotates bank bits. R16/R17 lesson:
// deeper register rings spill (allocator caps at 128 for 512thr; 256thr+ring22
// faults) -- concurrency must come from decorrelation, not more VGPRs.

#define CB 8
#define CH 56
#define CW 56
#define CC 64
#define CO 128
#define RS 72         // row stride in f16 (144 B)
#define CSTRIDE 450688  // B-copy stride in halfs: (901120 + 256)/2

typedef __attribute__((ext_vector_type(8))) _Float16 v8hf;  // MFMA A/B frag (4 VGPRs)
typedef __attribute__((ext_vector_type(16))) float f16f;    // 32x32 accumulator
typedef __attribute__((address_space(3))) const _Float16 lds_cf16;

// pair tables: p-th pair (i,j), i=0..9, j=i..9 (reference order)
__device__ constexpr int PII[55] = {0,0,0,0,0,0,0,0,0,0, 1,1,1,1,1,1,1,1,1, 2,2,2,2,2,2,2,2,
                                    3,3,3,3,3,3,3, 4,4,4,4,4,4, 5,5,5,5,5, 6,6,6,6, 7,7,7, 8,8, 9};
__device__ constexpr int PJJ[55] = {0,1,2,3,4,5,6,7,8,9, 1,2,3,4,5,6,7,8,9, 2,3,4,5,6,7,8,9,
                                    3,4,5,6,7,8,9, 4,5,6,7,8,9, 5,6,7,8,9, 6,7,8,9, 7,8,9, 8,9, 9};

// ---- prep: kernel [55][64][128] f32 -> BtF [55][4 ks][4 nq][64 lane][8] f16, x4 copies
// (exact per-wave MFMA B-fragment order: n = nq*32+(lane&31), k = ks*16+(lane>>5)*8+e)
// grid 220: p = blockIdx%55, copy = blockIdx/55
__global__ __launch_bounds__(256) void prep_kernel(const float* __restrict__ K,
                                                   _Float16* __restrict__ BtF) {
  __shared__ float tile[CC * CO];
  const int p = blockIdx.x % 55;
  const int c = blockIdx.x / 55;
  const int t = threadIdx.x;
  const float* src = K + (size_t)p * CC * CO;
#pragma unroll
  for (int e = 0; e < 8; ++e) {
    const int idx = t * 4 + e * 1024;
    *(float4*)&tile[idx] = *(const float4*)&src[idx];
  }
  __syncthreads();
  _Float16* dstc = BtF + (size_t)c * CSTRIDE;
#pragma unroll
  for (int e4 = 0; e4 < 4; ++e4) {
    const int idx = e4 * 256 + t;          // 0..1023 = ((ks*4 + nq)*64 + lane)
    const int lane = idx & 63;
    const int nqq = (idx >> 6) & 3;
    const int ksq = idx >> 8;
    const int n = nqq * 32 + (lane & 31);
    const int kb = ksq * 16 + (lane >> 5) * 8;
    _Float16 ov[8];
#pragma unroll
    for (int e = 0; e < 8; ++e)
      ov[e] = (_Float16)tile[(kb + e) * CO + n];
    *(v8hf*)(dstc + ((size_t)p * 1024 + idx) * 8) = *(const v8hf*)ov;
  }
}

// ---- main: one block per (b, row-pair). 256 threads = 4 waves, wave = N-quarter.
// Wave computes 4 m-tiles: rows h0,h0+1 x cols {0..31, 32..63(pad>=56)}.
__global__ __launch_bounds__(256, 1) void quad_kernel(const float* __restrict__ in,
                                                      const _Float16* __restrict__ BtF,
                                                      float* __restrict__ out) {
  __shared__ _Float16 rowsH[4][64][RS];  // rows h0-1..h0+2 (f16), col = w+1 halo, 36.9 KB

  const int t = threadIdx.x;
  const int b = blockIdx.x / (CH / 2);
  const int h0 = (blockIdx.x % (CH / 2)) * 2;

  // stage 4 input rows into LDS (f16) with zero halo (w=-1, w>=56) / zero OOB rows
  {
    const int col = t >> 2;          // 0..63
    const int cg = (t & 3) * 16;     // 16-channel group
    const int w = col - 1;
#pragma unroll
    for (int r = 0; r < 4; ++r) {
      const int hh = h0 + r - 1;
      const bool valid = (hh >= 0) && (hh < CH) && (w >= 0) && (w < CW);
      float4 v0 = make_float4(0.f, 0.f, 0.f, 0.f), v1 = v0, v2 = v0, v3 = v0;
      if (valid) {
        const float* s = in + (((size_t)(b * CH + hh)) * CW + w) * CC + cg;
        v0 = *(const float4*)(s);
        v1 = *(const float4*)(s + 4);
        v2 = *(const float4*)(s + 8);
        v3 = *(const float4*)(s + 12);
      }
      _Float16 pv[16];
      pv[0] = (_Float16)v0.x;  pv[1] = (_Float16)v0.y;  pv[2] = (_Float16)v0.z;  pv[3] = (_Float16)v0.w;
      pv[4] = (_Float16)v1.x;  pv[5] = (_Float16)v1.y;  pv[6] = (_Float16)v1.z;  pv[7] = (_Float16)v1.w;
      pv[8] = (_Float16)v2.x;  pv[9] = (_Float16)v2.y;  pv[10] = (_Float16)v2.z; pv[11] = (_Float16)v2.w;
      pv[12] = (_Float16)v3.x; pv[13] = (_Float16)v3.y; pv[14] = (_Float16)v3.z; pv[15] = (_Float16)v3.w;
      _Float16* d = &rowsH[r][col][cg];
      *(v8hf*)(d) = *(const v8hf*)&pv[0];
      *(v8hf*)(d + 8) = *(const v8hf*)&pv[8];
    }
  }

  const int lane = t & 63;
  const int nq = t >> 6;        // N-quarter 0..3
  const int ml = lane & 31;     // 32x32 MFMA: m (A) / n (B) lane index
  const int hk = lane >> 5;     // k-half selector
  const int h8 = hk * 8;

  f16f acc00, acc01, acc10, acc11;   // [row r][col-tile c]
#pragma unroll
  for (int r = 0; r < 16; ++r) { acc00[r] = 0.f; acc01[r] = 0.f; acc10[r] = 0.f; acc11[r] = 0.f; }

  // wave's B base: copy-decorrelated. csel spreads each XCD's CUs over 4 copies.
  const int csel = (blockIdx.x >> 3) & 3;
  const _Float16* Bw = BtF + (size_t)csel * CSTRIDE + (size_t)(nq * 64 + lane) * 8;
  const v8hf vone = {1, 1, 1, 1, 1, 1, 1, 1};

  // AS3 base pointer for asm ds_read (addrspacecast, 32-bit operand)
  lds_cf16* lds3 = (lds_cf16*)&rowsH[0][0][0];

  // prefetch ring, depth 11 (asm loads; issue order pinned by volatile)
  // flat step s = ks*55 + p; element offset = p*8192 + ks*2048
  v8hf ring[11];
#pragma unroll
  for (int p = 0; p < 11; ++p) {
    const _Float16* ba = Bw + (size_t)p * 8192;
    asm volatile("global_load_dwordx4 %0, %1, off" : "=v"(ring[p]) : "v"(ba));
  }

  __syncthreads();  // rowsH ready; no further barriers

#pragma unroll 1
  for (int ks = 0; ks < 4; ++ks) {  // K=64 channels in 4 steps of 16
    const int koff = ks * 16 + h8;
    // 24 shared shift vectors: sv{c}[rr*3+dx] = rowsH[rr][c*32+ml+dx][koff]
    v8hf sv0[12], sv1[12];
#pragma unroll
    for (int rr = 0; rr < 4; ++rr)
#pragma unroll
      for (int dx = 0; dx < 3; ++dx) {
        const int c0 = ml + dx;                         // max 33, in range
        int c1 = 32 + ml + dx; c1 = c1 > 63 ? 63 : c1;  // clamp (cols>=57 staged zero)
        lds_cf16* p0 = lds3 + (rr * 64 + c0) * RS + koff;
        lds_cf16* p1 = lds3 + (rr * 64 + c1) * RS + koff;
        asm volatile("ds_read_b128 %0, %1" : "=v"(sv0[rr * 3 + dx]) : "v"(p0));
        asm volatile("ds_read_b128 %0, %1" : "=v"(sv1[rr * 3 + dx]) : "v"(p1));
      }
    // one wait for all 24; ties the values so uses can't float above it
    asm volatile("s_waitcnt lgkmcnt(0)"
                 : "+v"(sv0[0]), "+v"(sv0[1]), "+v"(sv0[2]), "+v"(sv0[3]),
                   "+v"(sv0[4]), "+v"(sv0[5]), "+v"(sv0[6]), "+v"(sv0[7]),
                   "+v"(sv0[8]), "+v"(sv0[9]), "+v"(sv0[10]), "+v"(sv0[11]),
                   "+v"(sv1[0]), "+v"(sv1[1]), "+v"(sv1[2]), "+v"(sv1[3]),
                   "+v"(sv1[4]), "+v"(sv1[5]), "+v"(sv1[6]), "+v"(sv1[7]),
                   "+v"(sv1[8]), "+v"(sv1[9]), "+v"(sv1[10]), "+v"(sv1[11]));

    const int ksn = (ks < 3) ? ks + 1 : 3;  // tail prefetch clamp (redundant, harmless)
#pragma unroll
    for (int p = 0; p < 55; ++p) {
      // wait until the slot's load (issued 11 steps ago) has landed; 10 newer in flight
      asm volatile("s_waitcnt vmcnt(10)" : "+v"(ring[p % 11]));
      const v8hf bb = ring[p % 11];
      // refill the slot with flat step s+11 (p constant after unroll -> address folds)
      {
        const int p2 = (p < 44) ? p + 11 : p - 44;
        const int ks2 = (p < 44) ? ks : ksn;
        const _Float16* ba = Bw + (size_t)p2 * 8192 + (size_t)ks2 * 2048;
        asm volatile("global_load_dwordx4 %0, %1, off" : "=v"(ring[p % 11]) : "v"(ba));
      }
      const int pi = PII[p], pj = PJJ[p];
      v8hf a00, a01, a10, a11;
      if (pi == 0) {
        if (pj == 0) { a00 = vone; a01 = vone; a10 = vone; a11 = vone; }
        else {
          const int dy = (pj - 1) / 3, dx = (pj - 1) % 3;
          a00 = sv0[dy * 3 + dx];        a01 = sv1[dy * 3 + dx];
          a10 = sv0[(dy + 1) * 3 + dx];  a11 = sv1[(dy + 1) * 3 + dx];
        }
      } else {
        const int dyi = (pi - 1) / 3, dxi = (pi - 1) % 3;
        const int dyj = (pj - 1) / 3, dxj = (pj - 1) % 3;
        a00 = sv0[dyi * 3 + dxi] * sv0[dyj * 3 + dxj];
        a01 = sv1[dyi * 3 + dxi] * sv1[dyj * 3 + dxj];
        a10 = sv0[(dyi + 1) * 3 + dxi] * sv0[(dyj + 1) * 3 + dxj];
        a11 = sv1[(dyi + 1) * 3 + dxi] * sv1[(dyj + 1) * 3 + dxj];
      }
      acc00 = __builtin_amdgcn_mfma_f32_32x32x16_f16(a00, bb, acc00, 0, 0, 0);
      acc01 = __builtin_amdgcn_mfma_f32_32x32x16_f16(a01, bb, acc01, 0, 0, 0);
      acc10 = __builtin_amdgcn_mfma_f32_32x32x16_f16(a10, bb, acc10, 0, 0, 0);
      acc11 = __builtin_amdgcn_mfma_f32_32x32x16_f16(a11, bb, acc11, 0, 0, 0);
    }
  }
  // drain the 11 stray tail prefetches before the epilogue
  asm volatile("s_waitcnt vmcnt(0)");

  // epilogue: 32x32 C/D layout col=lane&31 (n), row=(reg&3)+8*(reg>>2)+4*(lane>>5) (m)
#pragma unroll
  for (int rw = 0; rw < 2; ++rw) {
    float* ob = out + ((size_t)(b * CH + h0 + rw) * CW) * CO + nq * 32 + ml;
    const f16f accc0 = rw ? acc10 : acc00;
    const f16f accc1 = rw ? acc11 : acc01;
#pragma unroll
    for (int r = 0; r < 16; ++r) {  // col-tile 0: w = 0..31, all real
      const int wp = (r & 3) + 8 * (r >> 2) + 4 * hk;
      ob[(size_t)wp * CO] = accc0[r];
    }
#pragma unroll
    for (int r = 0; r < 12; ++r) {  // col-tile 1: w = 32..55; regs 12..15 are w>=56 pad
      const int wp = 32 + (r & 3) + 8 * (r >> 2) + 4 * hk;
      ob[(size_t)wp * CO] = accc1[r];
    }
  }
}

extern "C" void kernel_launch(void* const* d_in, const int* in_sizes, int n_in,
                              void* d_out, int out_size, void* d_ws, size_t ws_size,
                              hipStream_t stream) {
  const float* in = (const float*)d_in[0];      // [8,56,56,64] f32
  const float* K = (const float*)d_in[1];       // [55,64,128] f32
  float* out = (float*)d_out;                   // [8,56,56,128] f32
  _Float16* BtF = (_Float16*)d_ws;              // 4 copies x (901,120 + 256) B = 3.6 MB
  (void)in_sizes; (void)n_in; (void)out_size; (void)ws_size;

  prep_kernel<<<220, 256, 0, stream>>>(K, BtF);
  quad_kernel<<<CB * (CH / 2), 256, 0, stream>>>(in, BtF, out);
}

// Round 7
// 89.317 us; speedup vs baseline: 1.6187x; 1.0150x over previous
//
#include <hip/hip_runtime.h>

// QuadraticConv2D: B=8 H=56 W=56 C=64 O=128, 55 quadratic pairs over (ones + 9 shifts)
// GEMM M=25088 pixels, K=55x64, N=128.
// R19 = R12 (256thr, wave=nq, 4 m-tiles/wave, 1 block/CU) with the B-prefetch
// register ring (depth 11, 44 VGPR) replaced by a WAVE-PRIVATE LDS RING of 26
// slots via global_load_lds (VGPR-free outstanding loads). Evidence ledger:
// R15 (2x waves, same ring) no gain; R18 (4-copy decorrelated B) no gain;
// R16/R17 (deeper reg rings) spill/fault. Surviving model: latency-bound B
// stream, ~4800 cyc effective latency, throughput ∝ per-wave outstanding.
// Depth 11 -> 27 (26 LDS slots + 1 reg read-ahead stage). Per iter: refill slot
// s%26 (step s already in regs) -> vmcnt(25) (step s+1 landed; in-order counting
// makes early landings safe) -> ds_read bb_next -> lgkmcnt(1) ties bb_cur.
// No barriers in the K loop: each wave consumes only its own nq quarter.
// LDS: rowsH 36.9 KB + ldsB 104 KB = 140 KB (<= 160 KB). 224 blocks, 1/CU.

#define CB 8
#define CH 56
#define CW 56
#define CC 64
#define CO 128
#define RS 72     // row stride in f16 (144 B)
#define DSLOT 26  // LDS B-ring slots per wave

typedef __attribute__((ext_vector_type(8))) _Float16 v8hf;  // MFMA A/B frag (4 VGPRs)
typedef __attribute__((ext_vector_type(16))) float f16f;    // 32x32 accumulator
typedef __attribute__((address_space(3))) const _Float16 lds_cf16;
typedef __attribute__((address_space(3))) _Float16 lds_f16;
typedef const __attribute__((address_space(1))) void* gas_t;  // global AS ptr for builtin
typedef __attribute__((address_space(3))) void* las_t;        // LDS AS ptr for builtin

// pair tables: p-th pair (i,j), i=0..9, j=i..9 (reference order)
__device__ constexpr int PII[55] = {0,0,0,0,0,0,0,0,0,0, 1,1,1,1,1,1,1,1,1, 2,2,2,2,2,2,2,2,
                                    3,3,3,3,3,3,3, 4,4,4,4,4,4, 5,5,5,5,5, 6,6,6,6, 7,7,7, 8,8, 9};
__device__ constexpr int PJJ[55] = {0,1,2,3,4,5,6,7,8,9, 1,2,3,4,5,6,7,8,9, 2,3,4,5,6,7,8,9,
                                    3,4,5,6,7,8,9, 4,5,6,7,8,9, 5,6,7,8,9, 6,7,8,9, 7,8,9, 8,9, 9};

// ---- prep: kernel [55][64][128] f32 -> BtF [55][4 ks][4 nq][64 lane][8] f16
// (exact per-wave MFMA B-fragment order: n = nq*32+(lane&31), k = ks*16+(lane>>5)*8+e)
__global__ __launch_bounds__(256) void prep_kernel(const float* __restrict__ K,
                                                   _Float16* __restrict__ BtF) {
  __shared__ float tile[CC * CO];
  const int p = blockIdx.x;
  const int t = threadIdx.x;
  const float* src = K + (size_t)p * CC * CO;
#pragma unroll
  for (int e = 0; e < 8; ++e) {
    const int idx = t * 4 + e * 1024;
    *(float4*)&tile[idx] = *(const float4*)&src[idx];
  }
  __syncthreads();
#pragma unroll
  for (int e4 = 0; e4 < 4; ++e4) {
    const int idx = e4 * 256 + t;          // 0..1023 = ((ks*4 + nq)*64 + lane)
    const int lane = idx & 63;
    const int nqq = (idx >> 6) & 3;
    const int ksq = idx >> 8;
    const int n = nqq * 32 + (lane & 31);
    const int kb = ksq * 16 + (lane >> 5) * 8;
    _Float16 ov[8];
#pragma unroll
    for (int e = 0; e < 8; ++e)
      ov[e] = (_Float16)tile[(kb + e) * CO + n];
    *(v8hf*)(BtF + ((size_t)p * 1024 + idx) * 8) = *(const v8hf*)ov;
  }
}

// ---- main: one block per (b, row-pair). 256 threads = 4 waves, wave = N-quarter.
// Wave computes 4 m-tiles: rows h0,h0+1 x cols {0..31, 32..63(pad>=56)}.
__global__ __launch_bounds__(256, 1) void quad_kernel(const float* __restrict__ in,
                                                      const _Float16* __restrict__ BtF,
                                                      float* __restrict__ out) {
  __shared__ _Float16 rowsH[4][64][RS];          // 36.9 KB input rows
  __shared__ _Float16 ldsB[DSLOT][4][64][8];     // 104 KB B ring: [slot][nq][lane][8]

  const int t = threadIdx.x;
  const int b = blockIdx.x / (CH / 2);
  const int h0 = (blockIdx.x % (CH / 2)) * 2;

  // stage 4 input rows into LDS (f16) with zero halo (w=-1, w>=56) / zero OOB rows
  {
    const int col = t >> 2;          // 0..63
    const int cg = (t & 3) * 16;     // 16-channel group
    const int w = col - 1;
#pragma unroll
    for (int r = 0; r < 4; ++r) {
      const int hh = h0 + r - 1;
      const bool valid = (hh >= 0) && (hh < CH) && (w >= 0) && (w < CW);
      float4 v0 = make_float4(0.f, 0.f, 0.f, 0.f), v1 = v0, v2 = v0, v3 = v0;
      if (valid) {
        const float* s = in + (((size_t)(b * CH + hh)) * CW + w) * CC + cg;
        v0 = *(const float4*)(s);
        v1 = *(const float4*)(s + 4);
        v2 = *(const float4*)(s + 8);
        v3 = *(const float4*)(s + 12);
      }
      _Float16 pv[16];
      pv[0] = (_Float16)v0.x;  pv[1] = (_Float16)v0.y;  pv[2] = (_Float16)v0.z;  pv[3] = (_Float16)v0.w;
      pv[4] = (_Float16)v1.x;  pv[5] = (_Float16)v1.y;  pv[6] = (_Float16)v1.z;  pv[7] = (_Float16)v1.w;
      pv[8] = (_Float16)v2.x;  pv[9] = (_Float16)v2.y;  pv[10] = (_Float16)v2.z; pv[11] = (_Float16)v2.w;
      pv[12] = (_Float16)v3.x; pv[13] = (_Float16)v3.y; pv[14] = (_Float16)v3.z; pv[15] = (_Float16)v3.w;
      _Float16* d = &rowsH[r][col][cg];
      *(v8hf*)(d) = *(const v8hf*)&pv[0];
      *(v8hf*)(d + 8) = *(const v8hf*)&pv[8];
    }
  }

  const int lane = t & 63;
  const int nq = t >> 6;        // N-quarter 0..3
  const int ml = lane & 31;     // 32x32 MFMA: m (A) / n (B) lane index
  const int hk = lane >> 5;     // k-half selector
  const int h8 = hk * 8;

  f16f acc00, acc01, acc10, acc11;   // [row r][col-tile c]
#pragma unroll
  for (int r = 0; r < 16; ++r) { acc00[r] = 0.f; acc01[r] = 0.f; acc10[r] = 0.f; acc11[r] = 0.f; }

  // wave's B base: BtF + ((p*4 + ks)*4 + nq)*512 + lane*8 (coalesced 1 KB per wave-load)
  const _Float16* Bw = BtF + (size_t)(nq * 64 + lane) * 8;
  const v8hf vone = {1, 1, 1, 1, 1, 1, 1, 1};

  // AS3 pointers
  lds_cf16* lds3 = (lds_cf16*)&rowsH[0][0][0];
  lds_f16* ldsBw = (lds_f16*)&ldsB[0][nq][0][0];        // wave-uniform DMA dest base
  lds_cf16* ldsBrL = (lds_cf16*)&ldsB[0][nq][0][0] + lane * 8;  // per-lane read base

  // prologue: fill the 26-slot LDS ring with flat steps 0..25 (all ks=0)
  // flat step s = ks*55 + p; element offset = p*8192 + ks*2048; slot = s % 26
#pragma unroll
  for (int s0 = 0; s0 < DSLOT; ++s0) {
    const _Float16* ga = Bw + (size_t)s0 * 8192;
    __builtin_amdgcn_global_load_lds((gas_t)ga, (las_t)(ldsBw + s0 * 2048), 16, 0, 0);
  }

  __syncthreads();  // rowsH ready; no further barriers

  // read-ahead stage: bb_cur = step 0
  v8hf bb_cur, bb_nxt;
  asm volatile("s_waitcnt vmcnt(25)");   // step 0 landed (26 issued, >=1 landed)
  asm volatile("ds_read_b128 %0, %1" : "=v"(bb_cur) : "v"(ldsBrL));

  int slR = 1;  // slot of step s+1 (uniform)
  int slW = 0;  // slot of step s = refill target (uniform)

#pragma unroll 1
  for (int ks = 0; ks < 4; ++ks) {  // K=64 channels in 4 steps of 16
    const int koff = ks * 16 + h8;
    // 24 shared shift vectors: sv{c}[rr*3+dx] = rowsH[rr][c*32+ml+dx][koff]
    v8hf sv0[12], sv1[12];
#pragma unroll
    for (int rr = 0; rr < 4; ++rr)
#pragma unroll
      for (int dx = 0; dx < 3; ++dx) {
        const int c0 = ml + dx;                         // max 33, in range
        int c1 = 32 + ml + dx; c1 = c1 > 63 ? 63 : c1;  // clamp (cols>=57 staged zero)
        lds_cf16* p0 = lds3 + (rr * 64 + c0) * RS + koff;
        lds_cf16* p1 = lds3 + (rr * 64 + c1) * RS + koff;
        asm volatile("ds_read_b128 %0, %1" : "=v"(sv0[rr * 3 + dx]) : "v"(p0));
        asm volatile("ds_read_b128 %0, %1" : "=v"(sv1[rr * 3 + dx]) : "v"(p1));
      }
    // one wait for all 24 (also covers any pending bb read); ties the values
    asm volatile("s_waitcnt lgkmcnt(0)"
                 : "+v"(sv0[0]), "+v"(sv0[1]), "+v"(sv0[2]), "+v"(sv0[3]),
                   "+v"(sv0[4]), "+v"(sv0[5]), "+v"(sv0[6]), "+v"(sv0[7]),
                   "+v"(sv0[8]), "+v"(sv0[9]), "+v"(sv0[10]), "+v"(sv0[11]),
                   "+v"(sv1[0]), "+v"(sv1[1]), "+v"(sv1[2]), "+v"(sv1[3]),
                   "+v"(sv1[4]), "+v"(sv1[5]), "+v"(sv1[6]), "+v"(sv1[7]),
                   "+v"(sv1[8]), "+v"(sv1[9]), "+v"(sv1[10]), "+v"(sv1[11]),
                   "+v"(bb_cur));

#pragma unroll
    for (int p = 0; p < 55; ++p) {
      // refill: flat step s+26 -> slot slW (slot's step-s data already in bb_cur).
      // s+26 = ks*55 + p + 26: p<29 -> same ks, p+26; else next ks (wrap 3->0), p-29.
      {
        const int p2 = (p < 29) ? p + 26 : p - 29;
        const int ks2 = (p < 29) ? ks : ((ks == 3) ? 0 : ks + 1);
        const _Float16* ga = Bw + (size_t)p2 * 8192 + (size_t)ks2 * 2048;
        __builtin_amdgcn_global_load_lds((gas_t)ga, (las_t)(ldsBw + slW * 2048), 16, 0, 0);
      }
      // issued = 26 + (s+1); vmcnt(25) => landed >= s+2 => step s+1 is in LDS
      asm volatile("s_waitcnt vmcnt(25)");
      {
        lds_cf16* rp = ldsBrL + slR * 2048;
        asm volatile("ds_read_b128 %0, %1" : "=v"(bb_nxt) : "v"(rp));
      }
      // allow only the newest LDS op (bb_nxt) outstanding => bb_cur complete
      asm volatile("s_waitcnt lgkmcnt(1)" : "+v"(bb_cur));

      const int pi = PII[p], pj = PJJ[p];
      v8hf a00, a01, a10, a11;
      if (pi == 0) {
        if (pj == 0) { a00 = vone; a01 = vone; a10 = vone; a11 = vone; }
        else {
          const int dy = (pj - 1) / 3, dx = (pj - 1) % 3;
          a00 = sv0[dy * 3 + dx];        a01 = sv1[dy * 3 + dx];
          a10 = sv0[(dy + 1) * 3 + dx];  a11 = sv1[(dy + 1) * 3 + dx];
        }
      } else {
        const int dyi = (pi - 1) / 3, dxi = (pi - 1) % 3;
        const int dyj = (pj - 1) / 3, dxj = (pj - 1) % 3;
        a00 = sv0[dyi * 3 + dxi] * sv0[dyj * 3 + dxj];
        a01 = sv1[dyi * 3 + dxi] * sv1[dyj * 3 + dxj];
        a10 = sv0[(dyi + 1) * 3 + dxi] * sv0[(dyj + 1) * 3 + dxj];
        a11 = sv1[(dyi + 1) * 3 + dxi] * sv1[(dyj + 1) * 3 + dxj];
      }
      acc00 = __builtin_amdgcn_mfma_f32_32x32x16_f16(a00, bb_cur, acc00, 0, 0, 0);
      acc01 = __builtin_amdgcn_mfma_f32_32x32x16_f16(a01, bb_cur, acc01, 0, 0, 0);
      acc10 = __builtin_amdgcn_mfma_f32_32x32x16_f16(a10, bb_cur, acc10, 0, 0, 0);
      acc11 = __builtin_amdgcn_mfma_f32_32x32x16_f16(a11, bb_cur, acc11, 0, 0, 0);

      bb_cur = bb_nxt;
      slW = slR;
      slR = (slR == DSLOT - 1) ? 0 : slR + 1;
    }
  }
  // drain the stray tail refills before the epilogue
  asm volatile("s_waitcnt vmcnt(0)");

  // epilogue: 32x32 C/D layout col=lane&31 (n), row=(reg&3)+8*(reg>>2)+4*(lane>>5) (m)
#pragma unroll
  for (int rw = 0; rw < 2; ++rw) {
    float* ob = out + ((size_t)(b * CH + h0 + rw) * CW) * CO + nq * 32 + ml;
    const f16f accc0 = rw ? acc10 : acc00;
    const f16f accc1 = rw ? acc11 : acc01;
#pragma unroll
    for (int r = 0; r < 16; ++r) {  // col-tile 0: w = 0..31, all real
      const int wp = (r & 3) + 8 * (r >> 2) + 4 * hk;
      ob[(size_t)wp * CO] = accc0[r];
    }
#pragma unroll
    for (int r = 0; r < 12; ++r) {  // col-tile 1: w = 32..55; regs 12..15 are w>=56 pad
      const int wp = 32 + (r & 3) + 8 * (r >> 2) + 4 * hk;
      ob[(size_t)wp * CO] = accc1[r];
    }
  }
}

extern "C" void kernel_launch(void* const* d_in, const int* in_sizes, int n_in,
                              void* d_out, int out_size, void* d_ws, size_t ws_size,
                              hipStream_t stream) {
  const float* in = (const float*)d_in[0];      // [8,56,56,64] f32
  const float* K = (const float*)d_in[1];       // [55,64,128] f32
  float* out = (float*)d_out;                   // [8,56,56,128] f32
  _Float16* BtF = (_Float16*)d_ws;              // [55][4][4][64][8] f16 = 901,120 B
  (void)in_sizes; (void)n_in; (void)out_size; (void)ws_size;

  prep_kernel<<<55, 256, 0, stream>>>(K, BtF);
  quad_kernel<<<CB * (CH / 2), 256, 0, stream>>>(in, BtF, out);
}